// Round 7
// baseline (494.629 us; speedup 1.0000x reference)
//
#include <hip/hip_runtime.h>
#include <hip/hip_bf16.h>

// RGCN 2-layer forward, f32 accuracy. CSR counting-sort; layer-1 GEMM via
// split-bf16 (hi+lo) 3-term MFMA (error ~2^-17 rel), split-K=2 for occupancy.
// L1: aggH/aggL[seg][128] = bf16-split mean x[src];
//     part[kq] = [agg|x]_kq @ [W1;Wr1]_kq  (MFMA, 2 K-halves, 782 blocks)
// L2: hv = relu(part0+part1+b1) folded into t[n,0:18] = hv @ [W2_r(:,0:2).. | Wr2];
//     out = sum_r mean t[src,2r:2r+2] + t[n,16:18] + b2.

#define NR 8
#define DH 128
#define KCH 18  // kc chunks (32-wide) per split-K block; 36 total

typedef short short8 __attribute__((ext_vector_type(8)));
typedef float f32x4 __attribute__((ext_vector_type(4)));

__device__ inline ushort f2bf(float v) {
  __hip_bfloat16 b = __float2bfloat16(v);
  return *reinterpret_cast<ushort*>(&b);
}
__device__ inline float bf2f(ushort u) {
  __hip_bfloat16 b;
  *reinterpret_cast<ushort*>(&b) = u;
  return __bfloat162float(b);
}
union U128 { uint4 u; short8 s; };

// ---------- counting sort ----------
__global__ __launch_bounds__(256) void k_hist(const int* __restrict__ dst, const int* __restrict__ et,
                                              int* __restrict__ hist, int E) {
  int e = blockIdx.x * 256 + threadIdx.x;
  if (e < E) atomicAdd(&hist[dst[e] * NR + et[e]], 1);
}

__global__ __launch_bounds__(256) void k_scan_local(const int* __restrict__ hist, int* __restrict__ offs,
                                                    int* __restrict__ blksum, int S) {
  __shared__ int tsum[256];
  int tid = threadIdx.x;
  int base = blockIdx.x * 1024 + tid * 4;
  int v[4], tot = 0;
  #pragma unroll
  for (int i = 0; i < 4; i++) { v[i] = (base + i < S) ? hist[base + i] : 0; tot += v[i]; }
  tsum[tid] = tot;
  __syncthreads();
  for (int off = 1; off < 256; off <<= 1) {
    int val = tsum[tid];
    int add = (tid >= off) ? tsum[tid - off] : 0;
    __syncthreads();
    tsum[tid] = val + add;
    __syncthreads();
  }
  int run = tsum[tid] - tot;
  #pragma unroll
  for (int i = 0; i < 4; i++) {
    if (base + i < S) offs[base + i] = run;
    run += v[i];
  }
  if (tid == 255) blksum[blockIdx.x] = tsum[255];
}

__global__ __launch_bounds__(512) void k_scan_blk(const int* __restrict__ blksum, int* __restrict__ blkoff, int NB) {
  __shared__ int s[512];
  int tid = threadIdx.x;
  int v = (tid < NB) ? blksum[tid] : 0;
  s[tid] = v;
  __syncthreads();
  for (int off = 1; off < 512; off <<= 1) {
    int val = s[tid];
    int add = (tid >= off) ? s[tid - off] : 0;
    __syncthreads();
    s[tid] = val + add;
    __syncthreads();
  }
  if (tid < NB) blkoff[tid] = s[tid] - v;
}

__global__ __launch_bounds__(256) void k_scan_add(int* __restrict__ offs, const int* __restrict__ blkoff, int S) {
  int tid = threadIdx.x;
  int base = blockIdx.x * 1024 + tid * 4;
  int add = blkoff[blockIdx.x];
  #pragma unroll
  for (int i = 0; i < 4; i++)
    if (base + i < S) offs[base + i] += add;
}

__global__ __launch_bounds__(256) void k_scatter_idx(const int* __restrict__ src, const int* __restrict__ dst,
                                                     const int* __restrict__ et, int* __restrict__ offs,
                                                     int* __restrict__ sorted_src, int E) {
  int e = blockIdx.x * 256 + threadIdx.x;
  if (e >= E) return;
  int seg = dst[e] * NR + et[e];
  int pos = atomicAdd(&offs[seg], 1);
  sorted_src[pos] = src[e];
}

// ---------- W split+transpose: Wt[col][k], k in [0,1152) ----------
__global__ __launch_bounds__(128) void k_wsplit(const float* __restrict__ W1, const float* __restrict__ Wr1,
                                                ushort* __restrict__ WtH, ushort* __restrict__ WtL) {
  int c = blockIdx.x;
  int k = blockIdx.y * 128 + threadIdx.x;
  float v = (k < 1024) ? W1[(size_t)k * 128 + c] : Wr1[(size_t)(k - 1024) * 128 + c];
  ushort hi = f2bf(v);
  ushort lo = f2bf(v - bf2f(hi));
  WtH[(size_t)c * 1152 + k] = hi;
  WtL[(size_t)c * 1152 + k] = lo;
}

// ---------- layer 1 aggregate: one wave per segment, writes bf16 hi/lo planes ----------
__global__ __launch_bounds__(256) void k_agg1(const int* __restrict__ offs, const int* __restrict__ hist,
                                              const int* __restrict__ sorted_src, const float* __restrict__ x,
                                              ushort* __restrict__ aggH, ushort* __restrict__ aggL, int S) {
  int tid = threadIdx.x;
  int seg = blockIdx.x * 4 + (tid >> 6);
  int lane = tid & 63;
  if (seg >= S) return;
  int end = offs[seg];
  int cnt = hist[seg];
  int st = end - cnt;
  float ax = 0.f, ay = 0.f;
  int i = st;
  for (; i + 4 <= end; i += 4) {
    int s0 = sorted_src[i + 0];
    int s1 = sorted_src[i + 1];
    int s2 = sorted_src[i + 2];
    int s3 = sorted_src[i + 3];
    float2 v0 = *(const float2*)(x + (size_t)s0 * DH + lane * 2);
    float2 v1 = *(const float2*)(x + (size_t)s1 * DH + lane * 2);
    float2 v2 = *(const float2*)(x + (size_t)s2 * DH + lane * 2);
    float2 v3 = *(const float2*)(x + (size_t)s3 * DH + lane * 2);
    ax += (v0.x + v1.x) + (v2.x + v3.x);
    ay += (v0.y + v1.y) + (v2.y + v3.y);
  }
  for (; i < end; i++) {
    int s = sorted_src[i];
    float2 v = *(const float2*)(x + (size_t)s * DH + lane * 2);
    ax += v.x;
    ay += v.y;
  }
  float inv = 1.f / fmaxf((float)cnt, 1.f);
  ax *= inv;
  ay *= inv;
  ushort hx = f2bf(ax), hy = f2bf(ay);
  ushort lx = f2bf(ax - bf2f(hx)), ly = f2bf(ay - bf2f(hy));
  ushort2 hv; hv.x = hx; hv.y = hy;
  ushort2 lv; lv.x = lx; lv.y = ly;
  *(ushort2*)(aggH + (size_t)seg * DH + lane * 2) = hv;
  *(ushort2*)(aggL + (size_t)seg * DH + lane * 2) = lv;
}

// ---------- layer 1 MFMA GEMM, split-K=2 ----------
// 256 thr = 4 waves (2x2), block tile 128x128, wave tile 64x64 (4x4 16x16x32 frags).
// blockIdx.y = kq selects K-half (18 kc chunks). A-frags direct from global;
// B staged in LDS with XOR-chunk swizzle (uniform b128 start banks, no conflicts).
// part[kq][n][c] = partial sum (no bias/relu).
__global__ __launch_bounds__(256) void k_gemm1_mfma(
    const ushort* __restrict__ aggH, const ushort* __restrict__ aggL,
    const float* __restrict__ xf,
    const ushort* __restrict__ WtH, const ushort* __restrict__ WtL,
    float* __restrict__ part, int N) {
  __shared__ ushort BsH[128 * 32];
  __shared__ ushort BsL[128 * 32];

  int tid = threadIdx.x;
  int w = tid >> 6, lane = tid & 63;
  int wr = w >> 1, wc = w & 1;
  int n0 = blockIdx.x * 128;
  int k0 = blockIdx.y * KCH;
  int kend = k0 + KCH;

  int frow = lane & 15;
  int g4 = lane >> 4;     // chunk group 0..3
  int fk8 = g4 * 8;

  // B staging: threads 0-127 hi plane, 128-255 lo plane; thread stages col sc's 32 k.
  int sp = tid >> 7;
  int sc = tid & 127;
  const ushort* wsrc = (sp ? WtL : WtH) + (size_t)sc * 1152;
  ushort* Bss = (sp ? BsL : BsH) + sc * 32;
  int sx = sc & 3;  // XOR key for chunk placement

  f32x4 acc[4][4];
  #pragma unroll
  for (int i = 0; i < 4; i++)
    #pragma unroll
    for (int j = 0; j < 4; j++) acc[i][j] = (f32x4){0.f, 0.f, 0.f, 0.f};

  uint4 praw[4][2];
  uint4 rb[4];
  short8 aH[4], aL[4];

  int arow[4];
  #pragma unroll
  for (int ft = 0; ft < 4; ft++) {
    int r = n0 + wr * 64 + ft * 16 + frow;
    arow[ft] = (r < N) ? r : (N - 1);  // clamp: OOB rows compute garbage, never stored
  }

  #define LOADA(kc)                                                              \
    {                                                                            \
      if ((kc) < 32) {                                                           \
        _Pragma("unroll")                                                        \
        for (int ft = 0; ft < 4; ft++) {                                         \
          size_t base = (size_t)arow[ft] * 1024 + (kc) * 32 + fk8;               \
          praw[ft][0] = *(const uint4*)(aggH + base);                            \
          praw[ft][1] = *(const uint4*)(aggL + base);                            \
        }                                                                        \
      } else {                                                                   \
        _Pragma("unroll")                                                        \
        for (int ft = 0; ft < 4; ft++) {                                         \
          const uint4* xp = (const uint4*)(xf + (size_t)arow[ft] * 128 +         \
                                           ((kc) - 32) * 32 + fk8);              \
          praw[ft][0] = xp[0];                                                   \
          praw[ft][1] = xp[1];                                                   \
        }                                                                        \
      }                                                                          \
    }
  #define LOADB(kc)                                                              \
    {                                                                            \
      const uint4* ws_ = (const uint4*)(wsrc + (kc) * 32);                       \
      rb[0] = ws_[0]; rb[1] = ws_[1]; rb[2] = ws_[2]; rb[3] = ws_[3];            \
    }

  LOADA(k0);
  LOADB(k0);

  for (int kc = k0; kc < kend; kc++) {
    // stage B with XOR-chunk placement: chunk i -> offset ((i^sx)*8)
    *(uint4*)(Bss + ((0 ^ sx) << 3)) = rb[0];
    *(uint4*)(Bss + ((1 ^ sx) << 3)) = rb[1];
    *(uint4*)(Bss + ((2 ^ sx) << 3)) = rb[2];
    *(uint4*)(Bss + ((3 ^ sx) << 3)) = rb[3];
    __syncthreads();

    // decode current A frags
    if (kc < 32) {
      #pragma unroll
      for (int ft = 0; ft < 4; ft++) {
        U128 uh, ul;
        uh.u = praw[ft][0];
        ul.u = praw[ft][1];
        aH[ft] = uh.s;
        aL[ft] = ul.s;
      }
    } else {
      #pragma unroll
      for (int ft = 0; ft < 4; ft++) {
        union { uint4 u[2]; float f[8]; } xx;
        xx.u[0] = praw[ft][0];
        xx.u[1] = praw[ft][1];
        short8 th, tl;
        #pragma unroll
        for (int j = 0; j < 8; j++) {
          ushort hb = f2bf(xx.f[j]);
          th[j] = (short)hb;
          tl[j] = (short)f2bf(xx.f[j] - bf2f(hb));
        }
        aH[ft] = th;
        aL[ft] = tl;
      }
    }

    if (kc + 1 < kend) {
      LOADA(kc + 1);
      LOADB(kc + 1);
    }

    #pragma unroll
    for (int ct = 0; ct < 4; ct++) {
      int gcol = wc * 64 + ct * 16 + frow;
      int boff = gcol * 32 + ((g4 ^ (frow & 3)) << 3);  // matches staging XOR
      const short8 bH = *(const short8*)(BsH + boff);
      const short8 bL = *(const short8*)(BsL + boff);
      #pragma unroll
      for (int ft = 0; ft < 4; ft++) {
        acc[ft][ct] = __builtin_amdgcn_mfma_f32_16x16x32_bf16(aH[ft], bH, acc[ft][ct], 0, 0, 0);
        acc[ft][ct] = __builtin_amdgcn_mfma_f32_16x16x32_bf16(aH[ft], bL, acc[ft][ct], 0, 0, 0);
        acc[ft][ct] = __builtin_amdgcn_mfma_f32_16x16x32_bf16(aL[ft], bH, acc[ft][ct], 0, 0, 0);
      }
    }
    __syncthreads();
  }
  #undef LOADA
  #undef LOADB

  // epilogue: raw partial sums; D layout col=lane&15, row=(lane>>4)*4+q
  float* po = part + (size_t)blockIdx.y * N * DH;
  int rbase = n0 + wr * 64 + (lane >> 4) * 4;
  #pragma unroll
  for (int ft = 0; ft < 4; ft++) {
    #pragma unroll
    for (int ct = 0; ct < 4; ct++) {
      int C = wc * 64 + ct * 16 + frow;
      #pragma unroll
      for (int q = 0; q < 4; q++) {
        int R = rbase + ft * 16 + q;
        if (R < N) po[(size_t)R * DH + C] = acc[ft][ct][q];
      }
    }
  }
}

// ---------- layer-2 transform (fused split-K combine + bias + relu) ----------
__global__ __launch_bounds__(256) void k_l2trans(const float* __restrict__ part, const float* __restrict__ b1,
                                                 const float* __restrict__ W2, const float* __restrict__ Wr2,
                                                 float* __restrict__ t, int N) {
  __shared__ float Wt[18 * 128];
  int tid = threadIdx.x;
  for (int i = tid; i < 2304; i += 256) {
    float v; int oc, d;
    if (i < 2048) { int r = i >> 8, rem = i & 255; d = rem >> 1; int c = rem & 1; oc = r * 2 + c; v = W2[i]; }
    else { int i2 = i - 2048; d = i2 >> 1; int c = i2 & 1; oc = 16 + c; v = Wr2[i2]; }
    Wt[oc * 128 + d] = v;
  }
  __syncthreads();
  int node = blockIdx.x * 4 + (tid >> 6);
  int lane = tid & 63;
  if (node >= N) return;
  size_t NP = (size_t)N * DH;
  float2 a0 = *(const float2*)(part + (size_t)node * DH + lane * 2);
  float2 a1 = *(const float2*)(part + NP + (size_t)node * DH + lane * 2);
  float2 bb = *(const float2*)(b1 + lane * 2);
  float2 hv;
  hv.x = fmaxf(a0.x + a1.x + bb.x, 0.f);
  hv.y = fmaxf(a0.y + a1.y + bb.y, 0.f);
  #pragma unroll
  for (int oc = 0; oc < 18; oc++) {
    float2 w = *(const float2*)(Wt + oc * 128 + lane * 2);
    float p = hv.x * w.x + hv.y * w.y;
    p += __shfl_xor(p, 32); p += __shfl_xor(p, 16); p += __shfl_xor(p, 8);
    p += __shfl_xor(p, 4);  p += __shfl_xor(p, 2);  p += __shfl_xor(p, 1);
    if (lane == 0) t[(size_t)node * 18 + oc] = p;
  }
}

// ---------- output: gather tiny t values per segment ----------
__global__ __launch_bounds__(256) void k_out2(const int* __restrict__ offs, const int* __restrict__ hist,
                                              const int* __restrict__ sorted_src, const float* __restrict__ t,
                                              const float* __restrict__ b2, float* __restrict__ out, int N) {
  int n = blockIdx.x * 256 + threadIdx.x;
  if (n >= N) return;
  float o0 = t[(size_t)n * 18 + 16] + b2[0];
  float o1 = t[(size_t)n * 18 + 17] + b2[1];
  #pragma unroll
  for (int r = 0; r < NR; r++) {
    int seg = n * NR + r;
    int en = offs[seg], cc = hist[seg];
    float s0 = 0.f, s1 = 0.f;
    for (int i = en - cc; i < en; i++) {
      int s = sorted_src[i];
      s0 += t[(size_t)s * 18 + r * 2];
      s1 += t[(size_t)s * 18 + r * 2 + 1];
    }
    float inv = 1.f / fmaxf((float)cc, 1.f);
    o0 += s0 * inv;
    o1 += s1 * inv;
  }
  out[(size_t)n * 2 + 0] = o0;
  out[(size_t)n * 2 + 1] = o1;
}

extern "C" void kernel_launch(void* const* d_in, const int* in_sizes, int n_in,
                              void* d_out, int out_size, void* d_ws, size_t ws_size,
                              hipStream_t stream) {
  const float* x   = (const float*)d_in[0];
  const int*   ei  = (const int*)d_in[1];
  const int*   et  = (const int*)d_in[2];
  const float* W1  = (const float*)d_in[3];
  const float* Wr1 = (const float*)d_in[4];
  const float* b1  = (const float*)d_in[5];
  const float* W2  = (const float*)d_in[6];
  const float* Wr2 = (const float*)d_in[7];
  const float* b2  = (const float*)d_in[8];
  float* out = (float*)d_out;

  int E = in_sizes[1] / 2;
  int N = in_sizes[0] / DH;
  int S = N * NR;
  const int* src = ei;
  const int* dst = ei + E;

  // ws layout: ints | aggH aggL | WtH WtL | part(2*N*128 f32) | t
  int* hist       = (int*)d_ws;                  // S
  int* offs       = hist + S;                    // S
  int* blksum     = offs + S;                    // 1024
  int* blkoff     = blksum + 1024;               // 1024
  int* sorted_src = blkoff + 1024;               // E
  size_t int_elems = (size_t)S * 2 + 2048 + E;
  int_elems = (int_elems + 3) & ~(size_t)3;      // 16B align
  ushort* aggH = (ushort*)(hist + int_elems);    // S*128
  ushort* aggL = aggH + (size_t)S * DH;          // S*128
  ushort* WtH  = aggL + (size_t)S * DH;          // 128*1152
  ushort* WtL  = WtH + 128 * 1152;               // 128*1152
  size_t ush_elems = (size_t)S * DH * 2 + 2 * 128 * 1152;  // 16B-aligned total
  float* part = (float*)(aggH + ush_elems);      // 2*N*128
  float* t    = part + (size_t)2 * N * DH;       // N*18

  hipMemsetAsync(hist, 0, sizeof(int) * (size_t)S, stream);

  k_hist<<<(E + 255) / 256, 256, 0, stream>>>(dst, et, hist, E);

  int NB = (S + 1023) / 1024;
  k_scan_local<<<NB, 256, 0, stream>>>(hist, offs, blksum, S);
  k_scan_blk<<<1, 512, 0, stream>>>(blksum, blkoff, NB);
  k_scan_add<<<NB, 256, 0, stream>>>(offs, blkoff, S);

  k_scatter_idx<<<(E + 255) / 256, 256, 0, stream>>>(src, dst, et, offs, sorted_src, E);

  k_wsplit<<<dim3(128, 9), 128, 0, stream>>>(W1, Wr1, WtH, WtL);

  k_agg1<<<(S + 3) / 4, 256, 0, stream>>>(offs, hist, sorted_src, x, aggH, aggL, S);

  k_gemm1_mfma<<<dim3((N + 127) / 128, 2), 256, 0, stream>>>(aggH, aggL, x, WtH, WtL, part, N);

  k_l2trans<<<(N + 3) / 4, 256, 0, stream>>>(part, b1, W2, Wr2, t, N);

  k_out2<<<(N + 255) / 256, 256, 0, stream>>>(offs, hist, sorted_src, t, b2, out, N);
}